// Round 6
// baseline (728.080 us; speedup 1.0000x reference)
//
#include <hip/hip_runtime.h>
#include <hip/hip_bf16.h>
#include <math.h>

// Problem constants
#define NROWS 8192
#define SPLITS 8          // k-slices (one per wave/cg) summed in k_fin
#define NPW   16          // n's per workgroup (grid 512)

typedef __bf16 bf16x8 __attribute__((ext_vector_type(8)));
typedef float  f32x4  __attribute__((ext_vector_type(4)));

__device__ __forceinline__ float bf2f(unsigned short u) {
    unsigned int v = ((unsigned int)u) << 16;
    float f; __builtin_memcpy(&f, &v, 4); return f;
}
__device__ __forceinline__ unsigned short f2bf(float f) {
    unsigned int u; __builtin_memcpy(&u, &f, 4);
    return (unsigned short)((u + 0x7fffu + ((u >> 16) & 1u)) >> 16);  // RNE
}
__device__ __forceinline__ float asf(unsigned int u) {
    float f; __builtin_memcpy(&f, &u, 4); return f;
}
__device__ __forceinline__ bf16x8 u4bf(uint4 u) {
    bf16x8 r; __builtin_memcpy(&r, &u, 16); return r;
}

// ---------------------------------------------------------------------------
// K1: fused forward MLP (vector f32). 256 wgs x 256 thr, 32 rows per wg.
// Produces out1 (f32), hp0f (f32 [8192][256]), hp1f (f32 [8192][256]).
// ---------------------------------------------------------------------------
__global__ __launch_bounds__(256) void k_fwd(
    const float* __restrict__ eps, const float* __restrict__ xc,
    const float* __restrict__ W0, const float* __restrict__ b0,
    const float* __restrict__ W1, const float* __restrict__ b1,
    const float* __restrict__ W2, const float* __restrict__ b2,
    const float* __restrict__ betap,
    float* __restrict__ hp0f, float* __restrict__ hp1f,
    float* __restrict__ out1)
{
    __shared__ float inpL[32 * 96];
    __shared__ float act0[32 * 256];
    __shared__ float act1[32 * 256];

    const int t  = threadIdx.x;
    const int n0 = blockIdx.x * 32;
    const float beta = betap[0];
    const float inv11 = 1.0f / 1.1f;

    for (int idx = t; idx < 32 * 96; idx += 256) {
        int r = idx / 96, c = idx - r * 96;
        float v = (c < 64) ? eps[(size_t)(n0 + r) * 64 + c]
                           : xc[(size_t)(n0 + r) * 32 + (c - 64)];
        inpL[idx] = v;
    }
    __syncthreads();

    // ---- layer 0 ----
    {
        const int j = t;
        float acc[32];
#pragma unroll
        for (int r = 0; r < 32; r++) acc[r] = 0.f;
        for (int cb = 0; cb < 12; cb++) {
            const float4 w0 = *(const float4*)(W0 + j * 96 + cb * 8);
            const float4 w1 = *(const float4*)(W0 + j * 96 + cb * 8 + 4);
#pragma unroll
            for (int r = 0; r < 32; r++) {
                const float4 x0 = *(const float4*)(inpL + r * 96 + cb * 8);
                const float4 x1 = *(const float4*)(inpL + r * 96 + cb * 8 + 4);
                acc[r] += w0.x * x0.x + w0.y * x0.y + w0.z * x0.z + w0.w * x0.w
                        + w1.x * x1.x + w1.y * x1.y + w1.z * x1.z + w1.w * x1.w;
            }
        }
        const float bj = b0[j];
#pragma unroll
        for (int r = 0; r < 32; r++) {
            float h = acc[r] + bj;
            float s = 1.f / (1.f + __expf(-beta * h));
            float f = h * s * inv11;
            float hp = beta * f + s * (inv11 - beta * f);
            act0[r * 256 + j] = f;
            hp0f[(size_t)(n0 + r) * 256 + j] = hp;
        }
    }
    __syncthreads();

    // ---- layer 1 ----
    {
        const int j = t;
        float acc[32];
#pragma unroll
        for (int r = 0; r < 32; r++) acc[r] = 0.f;
        for (int cb = 0; cb < 32; cb++) {
            const float4 w0 = *(const float4*)(W1 + j * 256 + cb * 8);
            const float4 w1 = *(const float4*)(W1 + j * 256 + cb * 8 + 4);
#pragma unroll
            for (int r = 0; r < 32; r++) {
                const float4 x0 = *(const float4*)(act0 + r * 256 + cb * 8);
                const float4 x1 = *(const float4*)(act0 + r * 256 + cb * 8 + 4);
                acc[r] += w0.x * x0.x + w0.y * x0.y + w0.z * x0.z + w0.w * x0.w
                        + w1.x * x1.x + w1.y * x1.y + w1.z * x1.z + w1.w * x1.w;
            }
        }
        const float bj = b1[j];
#pragma unroll
        for (int r = 0; r < 32; r++) {
            float h = acc[r] + bj;
            float s = 1.f / (1.f + __expf(-beta * h));
            float f = h * s * inv11;
            float hp = beta * f + s * (inv11 - beta * f);
            act1[r * 256 + j] = f;
            hp1f[(size_t)(n0 + r) * 256 + j] = hp;
        }
    }
    __syncthreads();

    // ---- layer 2 ----
    {
        const int j  = t & 63;
        const int rb = t >> 6;
        float acc[8];
#pragma unroll
        for (int rr = 0; rr < 8; rr++) acc[rr] = 0.f;
        for (int cb = 0; cb < 32; cb++) {
            const float4 w0 = *(const float4*)(W2 + j * 256 + cb * 8);
            const float4 w1 = *(const float4*)(W2 + j * 256 + cb * 8 + 4);
#pragma unroll
            for (int rr = 0; rr < 8; rr++) {
                const int r = rb * 8 + rr;
                const float4 x0 = *(const float4*)(act1 + r * 256 + cb * 8);
                const float4 x1 = *(const float4*)(act1 + r * 256 + cb * 8 + 4);
                acc[rr] += w0.x * x0.x + w0.y * x0.y + w0.z * x0.z + w0.w * x0.w
                         + w1.x * x1.x + w1.y * x1.y + w1.z * x1.z + w1.w * x1.w;
            }
        }
        const float bj = b2[j];
#pragma unroll
        for (int rr = 0; rr < 8; rr++) {
            const int r = rb * 8 + rr;
            out1[(size_t)(n0 + r) * 64 + j] = eps[(size_t)(n0 + r) * 64 + j] + acc[rr] + bj;
        }
    }
}

// ---------------------------------------------------------------------------
// K2: build swizzled W1 image (bf16, 128KB) for direct linear copy into LDS.
// Logical B[h][col] = W1[h*256+col]. Byte position:
//   j = h>>6 (panel), within: col*128 + (((h>>3)&7)*16 ^ ((col&7)<<4)) + (h&7)*2
// This is R2's verified 0-conflict 128B-row XOR geometry.
// ---------------------------------------------------------------------------
__global__ __launch_bounds__(256) void k_bpre(
    const float* __restrict__ W1, unsigned short* __restrict__ W1sw)
{
    const int col = blockIdx.x;    // 0..255
    const int h   = threadIdx.x;   // 0..255
    const float v = W1[h * 256 + col];
    const int j = h >> 6;
    const int s = (h >> 3) & 7;
    const int e = h & 7;
    const size_t byte = (size_t)j * 32768 + col * 128 + ((s * 16) ^ ((col & 7) << 4)) + e * 2;
    W1sw[byte >> 1] = f2bf(v);
}

// ---------------------------------------------------------------------------
// K3: batched per-sample GEMM:  M_n[d,k] = sum_h (W2[d,h]*hp1[n,h]) * W1[h,k]
// then diag partial: y[n,d] += sum_k M_n[d,k]*W0[k,d]*hp0[n,k].
// B = W1 static in LDS (written once). A-source W2-frags in registers.
// hp1/hp0 read from global (L1-resident, 32KB/wg). No barriers in n-loop.
// wg = 512 thr (8 waves = 8 k-col groups of 32), grid 512 (16 n each).
// ---------------------------------------------------------------------------
__global__ __launch_bounds__(512, 1) void k_jac(
    const float* __restrict__ hp0f, const float* __restrict__ hp1f,
    const unsigned short* __restrict__ W1sw,
    const float* __restrict__ W2, const float* __restrict__ W0,
    float* __restrict__ part)
{
    __shared__ __align__(16) unsigned char W1s[131072];

    const int t    = threadIdx.x;
    const int cg   = t >> 6;        // wave id = k-col group (0..7)
    const int lane = t & 63;
    const int l15  = lane & 15;
    const int lg   = lane >> 4;

    // ---- copy swizzled W1 image into LDS (linear, 16 iters x 8KB) ----
#pragma unroll
    for (int i = 0; i < 16; i++)
        *(uint4*)(W1s + i * 8192 + t * 16) =
            *(const uint4*)((const unsigned char*)W1sw + i * 8192 + t * 16);

    // ---- preload W2 A-frags into registers (bf16-packed, 128 VGPR) ----
    uint4 w2f[4][8];
#pragma unroll
    for (int mf = 0; mf < 4; mf++)
#pragma unroll
        for (int KS = 0; KS < 8; KS++) {
            const float* p = W2 + (size_t)(mf * 16 + l15) * 256 + KS * 32 + lg * 8;
            const float4 x0 = *(const float4*)(p);
            const float4 x1 = *(const float4*)(p + 4);
            unsigned int r0, r1, r2, r3;
            asm("v_cvt_pk_bf16_f32 %0, %1, %2" : "=v"(r0) : "v"(x0.x), "v"(x0.y));
            asm("v_cvt_pk_bf16_f32 %0, %1, %2" : "=v"(r1) : "v"(x0.z), "v"(x0.w));
            asm("v_cvt_pk_bf16_f32 %0, %1, %2" : "=v"(r2) : "v"(x1.x), "v"(x1.y));
            asm("v_cvt_pk_bf16_f32 %0, %1, %2" : "=v"(r3) : "v"(x1.z), "v"(x1.w));
            w2f[mf][KS] = make_uint4(r0, r1, r2, r3);
        }
    __syncthreads();

    const int n0 = blockIdx.x * NPW;

#pragma unroll 1
    for (int nl = 0; nl < NPW; nl++) {
        const int n = n0 + nl;
        const float* h1p = hp1f + (size_t)n * 256;
        const float* h0p = hp0f + (size_t)n * 256;

        f32x4 acc[4][2];
#pragma unroll
        for (int mf = 0; mf < 4; mf++) {
            acc[mf][0] = (f32x4){0.f, 0.f, 0.f, 0.f};
            acc[mf][1] = (f32x4){0.f, 0.f, 0.f, 0.f};
        }

#pragma unroll
        for (int KS = 0; KS < 8; KS++) {
            const float4 hA = *(const float4*)(h1p + KS * 32 + lg * 8);
            const float4 hB = *(const float4*)(h1p + KS * 32 + lg * 8 + 4);
            // B-frags from static LDS (R2 geometry)
            bf16x8 bfr[2];
#pragma unroll
            for (int cf = 0; cf < 2; cf++) {
                const int col = (cg * 2 + cf) * 16 + l15;
                const int cb = (((KS & 1) * 64 + lg * 16) ^ ((col & 7) << 4));
                bfr[cf] = *(const bf16x8*)(W1s + (KS >> 1) * 32768 + col * 128 + cb);
            }
#pragma unroll
            for (int mf = 0; mf < 4; mf++) {
                const uint4 w = w2f[mf][KS];
                unsigned int a0, a1, a2, a3;
                float lo, hi;
                lo = asf(w.x << 16) * hA.x;  hi = asf(w.x & 0xffff0000u) * hA.y;
                asm("v_cvt_pk_bf16_f32 %0, %1, %2" : "=v"(a0) : "v"(lo), "v"(hi));
                lo = asf(w.y << 16) * hA.z;  hi = asf(w.y & 0xffff0000u) * hA.w;
                asm("v_cvt_pk_bf16_f32 %0, %1, %2" : "=v"(a1) : "v"(lo), "v"(hi));
                lo = asf(w.z << 16) * hB.x;  hi = asf(w.z & 0xffff0000u) * hB.y;
                asm("v_cvt_pk_bf16_f32 %0, %1, %2" : "=v"(a2) : "v"(lo), "v"(hi));
                lo = asf(w.w << 16) * hB.z;  hi = asf(w.w & 0xffff0000u) * hB.w;
                asm("v_cvt_pk_bf16_f32 %0, %1, %2" : "=v"(a3) : "v"(lo), "v"(hi));
                const bf16x8 af = u4bf(make_uint4(a0, a1, a2, a3));
                acc[mf][0] = __builtin_amdgcn_mfma_f32_16x16x32_bf16(af, bfr[0], acc[mf][0], 0, 0, 0);
                acc[mf][1] = __builtin_amdgcn_mfma_f32_16x16x32_bf16(af, bfr[1], acc[mf][1], 0, 0, 0);
            }
        }

        // ---- epilogue: y[d] = sum_k M[d,k]*W0[k,d]*hp0[n,k] over this cg's k ----
        const int k0 = (cg * 2) * 16 + l15;
        const int k1 = (cg * 2 + 1) * 16 + l15;
        const float h0v0 = h0p[k0];
        const float h0v1 = h0p[k1];
        float vout[4][4];
#pragma unroll
        for (int mf = 0; mf < 4; mf++)
#pragma unroll
            for (int e = 0; e < 4; e++) {
                const int d = mf * 16 + lg * 4 + e;
                float v = acc[mf][0][e] * (W0[(size_t)k0 * 96 + d] * h0v0)
                        + acc[mf][1][e] * (W0[(size_t)k1 * 96 + d] * h0v1);
                v += __shfl_xor(v, 1, 64);
                v += __shfl_xor(v, 2, 64);
                v += __shfl_xor(v, 4, 64);
                v += __shfl_xor(v, 8, 64);
                vout[mf][e] = v;
            }
        if (l15 == 0) {
            float* pw = part + ((size_t)cg * NROWS + n) * 64;
#pragma unroll
            for (int mf = 0; mf < 4; mf++)
                *(float4*)(pw + mf * 16 + lg * 4) =
                    make_float4(vout[mf][0], vout[mf][1], vout[mf][2], vout[mf][3]);
        }
    }
}

// ---------------------------------------------------------------------------
// K4: finalize j[n] = sum_d log|1 + sum_s part[s][n][d]|. One wave per row.
// ---------------------------------------------------------------------------
__global__ __launch_bounds__(256) void k_fin(
    const float* __restrict__ part, float* __restrict__ outj)
{
    const int t = threadIdx.x;
    const int wavei = t >> 6, lane = t & 63;
    const int n = blockIdx.x * 4 + wavei;
    float ssum = 0.f;
#pragma unroll
    for (int s = 0; s < SPLITS; s++)
        ssum += part[((size_t)s * NROWS + n) * 64 + lane];
    float v = logf(fabsf(1.0f + ssum));
#pragma unroll
    for (int m = 1; m < 64; m <<= 1) v += __shfl_xor(v, m, 64);
    if (lane == 0) outj[n] = v;
}

// ---------------------------------------------------------------------------
extern "C" void kernel_launch(void* const* d_in, const int* in_sizes, int n_in,
                              void* d_out, int out_size, void* d_ws, size_t ws_size,
                              hipStream_t stream)
{
    const float* eps  = (const float*)d_in[0];
    const float* xc   = (const float*)d_in[1];
    const float* W0   = (const float*)d_in[2];
    const float* b0   = (const float*)d_in[3];
    const float* W1   = (const float*)d_in[4];
    const float* b1   = (const float*)d_in[5];
    const float* W2   = (const float*)d_in[6];
    const float* b2   = (const float*)d_in[7];
    const float* beta = (const float*)d_in[8];

    float* out1 = (float*)d_out;                       // 8192*64 f32
    float* outj = out1 + (size_t)NROWS * 64;           // 8192 f32

    char* ws = (char*)d_ws;
    float*          hp0f = (float*)(ws);                                        // 8 MB
    float*          hp1f = (float*)(ws + (size_t)8  * 1024 * 1024);             // 8 MB
    float*          part = (float*)(ws + (size_t)16 * 1024 * 1024);             // 16 MB
    unsigned short* W1sw = (unsigned short*)(ws + (size_t)32 * 1024 * 1024);    // 128 KB

    hipLaunchKernelGGL(k_bpre, dim3(256), dim3(256), 0, stream, W1, W1sw);
    hipLaunchKernelGGL(k_fwd, dim3(256), dim3(256), 0, stream,
                       eps, xc, W0, b0, W1, b1, W2, b2, beta, hp0f, hp1f, out1);
    hipLaunchKernelGGL(k_jac, dim3(NROWS / NPW), dim3(512), 0, stream,
                       hp0f, hp1f, W1sw, W2, W0, part);
    hipLaunchKernelGGL(k_fin, dim3(NROWS / 4), dim3(256), 0, stream, part, outj);
}